// Round 1
// baseline (846.134 us; speedup 1.0000x reference)
//
#include <hip/hip_runtime.h>
#include <hip/hip_bf16.h>

#define NCLS 80
#define CONF_T 0.25f
#define P1_BLOCKS 2048
#define P1_THREADS 256

// ws layout: [0] int first_fail ; [256 bytes ...] float partials[P1_BLOCKS]

__global__ void init_fail(int* fail, int N) { *fail = N; }

__device__ __forceinline__ float row_val(const float* __restrict__ pr,
                                         const float* __restrict__ boxes,
                                         int row, float* score_out) {
    const float4* p = (const float4*)(pr + (size_t)row * NCLS);
    float m = -INFINITY;
#pragma unroll
    for (int k = 0; k < NCLS / 4; ++k) {
        float4 v = p[k];
        m = fmaxf(m, fmaxf(fmaxf(v.x, v.y), fmaxf(v.z, v.w)));
    }
    float4 b = ((const float4*)boxes)[row];
    *score_out = m;
    return m + b.x + b.y + b.z + b.w;
}

__device__ __forceinline__ float block_reduce_sum(float v) {
    // wave = 64 lanes on gfx950
#pragma unroll
    for (int off = 32; off > 0; off >>= 1) v += __shfl_down(v, off, 64);
    __shared__ float sred[P1_THREADS / 64];
    int lane = threadIdx.x & 63;
    int wid  = threadIdx.x >> 6;
    if (lane == 0) sred[wid] = v;
    __syncthreads();
    float total = 0.f;
    if (threadIdx.x == 0) {
#pragma unroll
        for (int w = 0; w < P1_THREADS / 64; ++w) total += sred[w];
    }
    return total; // valid on thread 0 only
}

__global__ __launch_bounds__(P1_THREADS) void pass1(const float* __restrict__ pr,
                                                    const float* __restrict__ boxes,
                                                    float* __restrict__ partials,
                                                    int* __restrict__ fail,
                                                    int N, int R) {
    int cs = blockIdx.x * R;
    int ce = min(cs + R, N);
    float acc = 0.f;
    for (int row = cs + (int)threadIdx.x; row < ce; row += P1_THREADS) {
        float score;
        float v = row_val(pr, boxes, row, &score);
        if (score < CONF_T) atomicMin(fail, row);
        acc += v;
    }
    float tot = block_reduce_sum(acc);
    if (threadIdx.x == 0) partials[blockIdx.x] = tot;
}

__global__ __launch_bounds__(P1_THREADS) void pass2(const float* __restrict__ pr,
                                                    const float* __restrict__ boxes,
                                                    const float* __restrict__ partials,
                                                    const int* __restrict__ fail,
                                                    float* __restrict__ out,
                                                    int N, int R) {
    int ff = *fail;
    if (ff > N) ff = N;
    if (ff < 0) ff = 0;
    int full = ff / R; // chunks [0, full) fully kept
    float acc = 0.f;
    for (int c = (int)threadIdx.x; c < full; c += P1_THREADS) acc += partials[c];
    // straddling chunk: rows [full*R, ff) recomputed directly
    for (int row = full * R + (int)threadIdx.x; row < ff; row += P1_THREADS) {
        float score;
        acc += row_val(pr, boxes, row, &score);
    }
    float tot = block_reduce_sum(acc);
    if (threadIdx.x == 0) *out = tot;
}

extern "C" void kernel_launch(void* const* d_in, const int* in_sizes, int n_in,
                              void* d_out, int out_size, void* d_ws, size_t ws_size,
                              hipStream_t stream) {
    const float* pr    = (const float*)d_in[0];
    const float* boxes = (const float*)d_in[1];
    float* out = (float*)d_out;

    int N = in_sizes[1] / 4; // boxes are (N,4)
    int R = (N + P1_BLOCKS - 1) / P1_BLOCKS;

    int*   fail     = (int*)d_ws;
    float* partials = (float*)((char*)d_ws + 256);

    init_fail<<<1, 1, 0, stream>>>(fail, N);
    pass1<<<P1_BLOCKS, P1_THREADS, 0, stream>>>(pr, boxes, partials, fail, N, R);
    pass2<<<1, P1_THREADS, 0, stream>>>(pr, boxes, partials, fail, out, N, R);
}

// Round 2
// 819.551 us; speedup vs baseline: 1.0324x; 1.0324x over previous
//
#include <hip/hip_runtime.h>
#include <hip/hip_bf16.h>

#define NCLS 80
#define CONF_T 0.25f
#define P1_BLOCKS 2048
#define P1_THREADS 256
#define TILE_ROWS 128
#define TILE_F4 ((TILE_ROWS * NCLS) / 4)          // 2560 float4 = 40 KB
#define F4_PER_THREAD (TILE_F4 / P1_THREADS)      // 10

typedef __attribute__((address_space(1))) const void gvoid_t;
typedef __attribute__((address_space(3))) void lvoid_t;

// ws layout: [0] int first_fail ; [256 bytes ...] float partials[P1_BLOCKS]

__global__ void init_fail(int* fail, int N) { *fail = N; }

__device__ __forceinline__ float row_val_global(const float* __restrict__ pr,
                                                const float* __restrict__ boxes,
                                                int row, float* score_out) {
    const float4* p = (const float4*)(pr + (size_t)row * NCLS);
    float m = -INFINITY;
#pragma unroll
    for (int k = 0; k < NCLS / 4; ++k) {
        float4 v = p[k];
        m = fmaxf(m, fmaxf(fmaxf(v.x, v.y), fmaxf(v.z, v.w)));
    }
    float4 b = ((const float4*)boxes)[row];
    *score_out = m;
    return m + b.x + b.y + b.z + b.w;
}

__device__ __forceinline__ float block_reduce_sum(float v) {
#pragma unroll
    for (int off = 32; off > 0; off >>= 1) v += __shfl_down(v, off, 64);
    __shared__ float sred[P1_THREADS / 64];
    int lane = threadIdx.x & 63;
    int wid  = threadIdx.x >> 6;
    if (lane == 0) sred[wid] = v;
    __syncthreads();
    float total = 0.f;
    if (threadIdx.x == 0) {
#pragma unroll
        for (int w = 0; w < P1_THREADS / 64; ++w) total += sred[w];
    }
    return total; // valid on thread 0 only
}

__global__ __launch_bounds__(P1_THREADS) void pass1(const float* __restrict__ pr,
                                                    const float* __restrict__ boxes,
                                                    float* __restrict__ partials,
                                                    int* __restrict__ fail,
                                                    int N, int tiles_per_block) {
    __shared__ float4 sbuf[TILE_F4]; // 40 KB

    const int t = (int)threadIdx.x;
    const int tile0 = blockIdx.x * tiles_per_block;
    float acc = 0.f;

    for (int ti = 0; ti < tiles_per_block; ++ti) {
        const int row0 = (tile0 + ti) * TILE_ROWS;
        if (row0 >= N) break; // block-uniform

        if (row0 + TILE_ROWS <= N) {
            // ---- fast path: fully coalesced async stage into LDS ----
            const float4* gp = (const float4*)pr + (size_t)row0 * (NCLS / 4);
#pragma unroll
            for (int k = 0; k < F4_PER_THREAD; ++k) {
                int i4 = t + k * P1_THREADS;
                __builtin_amdgcn_global_load_lds((gvoid_t*)(gp + i4),
                                                 (lvoid_t*)(sbuf + i4), 16, 0, 0);
            }
            __syncthreads(); // drains vmcnt before LDS reads

            // ---- 2 threads per row: row max from LDS ----
            const int r = t >> 1, h = t & 1;
            const float4* rowp = (const float4*)((const float*)sbuf + r * NCLS + h * (NCLS / 2));
            float m = -INFINITY;
#pragma unroll
            for (int j = 0; j < NCLS / 8; ++j) { // 10 float4
                float4 v = rowp[j];
                m = fmaxf(m, fmaxf(fmaxf(v.x, v.y), fmaxf(v.z, v.w)));
            }
            m = fmaxf(m, __shfl_xor(m, 1, 64));
            if (h == 0) {
                int row = row0 + r;
                float4 b = ((const float4*)boxes)[row];
                if (m < CONF_T) atomicMin(fail, row);
                acc += m + b.x + b.y + b.z + b.w;
            }
            __syncthreads(); // sbuf reuse next tile
        } else {
            // ---- slow path: partial tail tile, direct global reads ----
            int ce = min(row0 + TILE_ROWS, N);
            for (int row = row0 + t; row < ce; row += P1_THREADS) {
                float score;
                float v = row_val_global(pr, boxes, row, &score);
                if (score < CONF_T) atomicMin(fail, row);
                acc += v;
            }
        }
    }

    float tot = block_reduce_sum(acc);
    if (t == 0) partials[blockIdx.x] = tot;
}

__global__ __launch_bounds__(P1_THREADS) void pass2(const float* __restrict__ pr,
                                                    const float* __restrict__ boxes,
                                                    const float* __restrict__ partials,
                                                    const int* __restrict__ fail,
                                                    float* __restrict__ out,
                                                    int N, int R) {
    int ff = *fail;
    if (ff > N) ff = N;
    if (ff < 0) ff = 0;

    int full, start;
    if (ff >= N) { full = P1_BLOCKS; start = N; }       // common case: keep everything
    else         { full = ff / R;    start = full * R; } // straddling chunk recomputed

    float acc = 0.f;
    for (int c = (int)threadIdx.x; c < full; c += P1_THREADS) acc += partials[c];
    for (int row = start + (int)threadIdx.x; row < ff; row += P1_THREADS) {
        float score;
        acc += row_val_global(pr, boxes, row, &score);
    }
    float tot = block_reduce_sum(acc);
    if (threadIdx.x == 0) *out = tot;
}

extern "C" void kernel_launch(void* const* d_in, const int* in_sizes, int n_in,
                              void* d_out, int out_size, void* d_ws, size_t ws_size,
                              hipStream_t stream) {
    const float* pr    = (const float*)d_in[0];
    const float* boxes = (const float*)d_in[1];
    float* out = (float*)d_out;

    int N = in_sizes[1] / 4; // boxes are (N,4)
    int tiles_total = (N + TILE_ROWS - 1) / TILE_ROWS;
    int tiles_per_block = (tiles_total + P1_BLOCKS - 1) / P1_BLOCKS;
    int R = tiles_per_block * TILE_ROWS; // rows per block (contiguous)

    int*   fail     = (int*)d_ws;
    float* partials = (float*)((char*)d_ws + 256);

    init_fail<<<1, 1, 0, stream>>>(fail, N);
    pass1<<<P1_BLOCKS, P1_THREADS, 0, stream>>>(pr, boxes, partials, fail, N, tiles_per_block);
    pass2<<<1, P1_THREADS, 0, stream>>>(pr, boxes, partials, fail, out, N, R);
}